// Round 8
// baseline (499.204 us; speedup 1.0000x reference)
//
#include <hip/hip_runtime.h>
#include <math.h>

#define NPTS 262144
#define KC 512
#define DD 64
#define MARGIN 8e-3f
#define SHIFT 32.0f
#define LOSCALE 2048.0f
#define INV2LO 0.0009765625f   // 2 / LOSCALE = 2^-10
#define BLOCK 512
#define PPB 256                // points per block (8 waves x 32)
#define SLICE 256              // == PPB -> llist cannot overflow

typedef _Float16 f16x8 __attribute__((ext_vector_type(8)));
typedef _Float16 f16x4 __attribute__((ext_vector_type(4)));
typedef float f32x4 __attribute__((ext_vector_type(4)));

__device__ __forceinline__ float csq_pairwise8(const float* row) {
    float r[8];
#pragma unroll
    for (int t = 0; t < 8; ++t) r[t] = __fmul_rn(row[t], row[t]);
#pragma unroll
    for (int b = 1; b < 8; ++b)
#pragma unroll
        for (int t = 0; t < 8; ++t)
            r[t] = __fadd_rn(r[t], __fmul_rn(row[8 * b + t], row[8 * b + t]));
    return __fadd_rn(__fadd_rn(__fadd_rn(r[0], r[1]), __fadd_rn(r[2], r[3])),
                     __fadd_rn(__fadd_rn(r[4], r[5]), __fadd_rn(r[6], r[7])));
}

__global__ __launch_bounds__(256) void prep_kernel(const float* __restrict__ c,
                                                   float* __restrict__ out_c,
                                                   float* __restrict__ csq) {
    int j = blockIdx.x * 256 + threadIdx.x;
    if (j < KC * DD) out_c[j] = c[j];
    if (j < KC) csq[j] = csq_pairwise8(c + j * DD);
}

#define LOADA(hi, lo, srow, skk)                                                   \
    {                                                                              \
        const float4* p_ = (const float4*)(x + (size_t)(pbase + (srow)*16 + lrow) * DD \
                                           + (skk)*32 + lgrp * 8);                 \
        float4 u0 = p_[0], u1 = p_[1];                                             \
        _Float16 t_; f16x8 h_, l_;                                                 \
        t_ = (_Float16)u0.x; h_[0] = t_; l_[0] = (_Float16)((u0.x - (float)t_) * LOSCALE); \
        t_ = (_Float16)u0.y; h_[1] = t_; l_[1] = (_Float16)((u0.y - (float)t_) * LOSCALE); \
        t_ = (_Float16)u0.z; h_[2] = t_; l_[2] = (_Float16)((u0.z - (float)t_) * LOSCALE); \
        t_ = (_Float16)u0.w; h_[3] = t_; l_[3] = (_Float16)((u0.w - (float)t_) * LOSCALE); \
        t_ = (_Float16)u1.x; h_[4] = t_; l_[4] = (_Float16)((u1.x - (float)t_) * LOSCALE); \
        t_ = (_Float16)u1.y; h_[5] = t_; l_[5] = (_Float16)((u1.y - (float)t_) * LOSCALE); \
        t_ = (_Float16)u1.z; h_[6] = t_; l_[6] = (_Float16)((u1.z - (float)t_) * LOSCALE); \
        t_ = (_Float16)u1.w; h_[7] = t_; l_[7] = (_Float16)((u1.w - (float)t_) * LOSCALE); \
        hi = h_; lo = l_;                                                          \
    }

// Packed best-2 update: key = (distbits & ~0x1FF) | k. dist > 0 always
// (d' = c_sq + 32 - 2*cross, |2*cross| <= 20) -> uint order == float order;
// equal stripped dist -> smaller k wins (first-index). 2 regs/row, min/max only.
#define UPDP(bb1, bb2, dv)                                          \
    {                                                               \
        unsigned key_ = (__float_as_uint(dv) & 0xFFFFFE00u) | (unsigned)kv; \
        unsigned mx_ = bb1 > key_ ? bb1 : key_;                     \
        bb1 = bb1 < key_ ? bb1 : key_;                              \
        bb2 = bb2 < mx_ ? bb2 : mx_;                                \
    }

#define MRGP(bb1, bb2)                                              \
    {                                                               \
        unsigned o1_ = (unsigned)__shfl_xor((int)bb1, dd);          \
        unsigned o2_ = (unsigned)__shfl_xor((int)bb2, dd);          \
        unsigned mx_ = bb1 > o1_ ? bb1 : o1_;                       \
        bb1 = bb1 < o1_ ? bb1 : o1_;                                \
        unsigned mn_ = o2_ < mx_ ? o2_ : mx_;                       \
        bb2 = bb2 < mn_ ? bb2 : mn_;                                \
    }

#define FLAGP(ss, rr, bb1, bb2)                                     \
    {                                                               \
        int p_ = pbase + (ss)*16 + lgrp * 4 + (rr);                 \
        float d1_ = __uint_as_float(bb1 & 0xFFFFFE00u);             \
        float d2_ = __uint_as_float(bb2 & 0xFFFFFE00u);             \
        if (d2_ - d1_ <= MARGIN) {                                  \
            int t_ = atomicAdd(lcnt, 1);                            \
            if (t_ < SLICE) llist[t_] = p_;                         \
            else out_assign[p_] = (float)(bb1 & 0x1FFu);            \
        } else {                                                    \
            out_assign[p_] = (float)(bb1 & 0x1FFu);                 \
        }                                                           \
    }

// Split-f16 MFMA approx (shifted dist, packed-key best-2 like R4's VGPR=32
// build) + LDS flag list + in-kernel exact rescore. State: 8 frags (32 regs)
// + 16 packed uints -> no scratch (R6/R7: 94 MB scratch WRITE_SIZE killed us).
__global__ __launch_bounds__(BLOCK, 4) void approx_kernel(const float* __restrict__ x,
                                                          const float* __restrict__ c,
                                                          const float* __restrict__ csq,
                                                          float* __restrict__ out_assign) {
    extern __shared__ char smem[];          // [0,32K) c_hi | [32K,64K) c_lo'
    float* scs = (float*)(smem + 65536);    // 512 f32: c_sq + 32
    int* llist = (int*)(smem + 67584);      // 256 int
    int* lcnt = (int*)(smem + 68608);

    int tid = threadIdx.x;
    if (tid == 0) *lcnt = 0;
    scs[tid] = csq[tid] + SHIFT;

    int wid = tid >> 6, lane = tid & 63;
    int lrow = lane & 15, lgrp = lane >> 4;
    int pbase = blockIdx.x * PPB + wid * 32;

    // A fragments (layout verified absmax=0 R4-R7): row=lane&15, k=kk*32+lgrp*8.
    f16x8 ahi00, alo00, ahi01, alo01, ahi10, alo10, ahi11, alo11;
    LOADA(ahi00, alo00, 0, 0)
    LOADA(ahi01, alo01, 0, 1)
    LOADA(ahi10, alo10, 1, 0)
    LOADA(ahi11, alo11, 1, 1)

    unsigned b1_00 = ~0u, b1_01 = ~0u, b1_02 = ~0u, b1_03 = ~0u;
    unsigned b1_10 = ~0u, b1_11 = ~0u, b1_12 = ~0u, b1_13 = ~0u;
    unsigned b2_00 = ~0u, b2_01 = ~0u, b2_02 = ~0u, b2_03 = ~0u;
    unsigned b2_10 = ~0u, b2_11 = ~0u, b2_12 = ~0u, b2_13 = ~0u;

    for (int pass = 0; pass < 2; ++pass) {
        __syncthreads();   // covers scs/lcnt on pass 0; pass-0 LDS reads on pass 1
        const float4* csrc = (const float4*)(c + (size_t)pass * 256 * DD);
#pragma unroll
        for (int it = 0; it < 8; ++it) {
            int chunk = tid + it * BLOCK;               // 4096 x 16B-src chunks
            int row = chunk >> 4, q = chunk & 15;
            float4 v = csrc[chunk];
            f16x4 h, l;
            _Float16 t;
            t = (_Float16)v.x; h[0] = t; l[0] = (_Float16)((v.x - (float)t) * LOSCALE);
            t = (_Float16)v.y; h[1] = t; l[1] = (_Float16)((v.y - (float)t) * LOSCALE);
            t = (_Float16)v.z; h[2] = t; l[2] = (_Float16)((v.z - (float)t) * LOSCALE);
            t = (_Float16)v.w; h[3] = t; l[3] = (_Float16)((v.w - (float)t) * LOSCALE);
            int off = row * 128 + (((q >> 1) ^ (row & 7)) << 4) + (q & 1) * 8;
            *(f16x4*)(smem + off) = h;
            *(f16x4*)(smem + 32768 + off) = l;
        }
        __syncthreads();

        int base0 = lrow * 128 + ((lgrp ^ (lrow & 7)) << 4);
        int csi = pass * 256 + lrow;
        for (int ct = 0; ct < 16; ++ct) {
            f16x8 bh0 = *(const f16x8*)(smem + base0);
            f16x8 bh1 = *(const f16x8*)(smem + (base0 ^ 64));
            f16x8 bl0 = *(const f16x8*)(smem + 32768 + base0);
            f16x8 bl1 = *(const f16x8*)(smem + 32768 + (base0 ^ 64));
            float cs = scs[csi];
            int kv = csi;

            f32x4 hh0 = {0.f, 0.f, 0.f, 0.f}, cr0 = {0.f, 0.f, 0.f, 0.f};
            hh0 = __builtin_amdgcn_mfma_f32_16x16x32_f16(ahi00, bh0, hh0, 0, 0, 0);
            hh0 = __builtin_amdgcn_mfma_f32_16x16x32_f16(ahi01, bh1, hh0, 0, 0, 0);
            cr0 = __builtin_amdgcn_mfma_f32_16x16x32_f16(ahi00, bl0, cr0, 0, 0, 0);
            cr0 = __builtin_amdgcn_mfma_f32_16x16x32_f16(ahi01, bl1, cr0, 0, 0, 0);
            cr0 = __builtin_amdgcn_mfma_f32_16x16x32_f16(alo00, bh0, cr0, 0, 0, 0);
            cr0 = __builtin_amdgcn_mfma_f32_16x16x32_f16(alo01, bh1, cr0, 0, 0, 0);
            UPDP(b1_00, b2_00, __fmaf_rn(-INV2LO, cr0[0], __fmaf_rn(-2.0f, hh0[0], cs)))
            UPDP(b1_01, b2_01, __fmaf_rn(-INV2LO, cr0[1], __fmaf_rn(-2.0f, hh0[1], cs)))
            UPDP(b1_02, b2_02, __fmaf_rn(-INV2LO, cr0[2], __fmaf_rn(-2.0f, hh0[2], cs)))
            UPDP(b1_03, b2_03, __fmaf_rn(-INV2LO, cr0[3], __fmaf_rn(-2.0f, hh0[3], cs)))

            f32x4 hh1 = {0.f, 0.f, 0.f, 0.f}, cr1 = {0.f, 0.f, 0.f, 0.f};
            hh1 = __builtin_amdgcn_mfma_f32_16x16x32_f16(ahi10, bh0, hh1, 0, 0, 0);
            hh1 = __builtin_amdgcn_mfma_f32_16x16x32_f16(ahi11, bh1, hh1, 0, 0, 0);
            cr1 = __builtin_amdgcn_mfma_f32_16x16x32_f16(ahi10, bl0, cr1, 0, 0, 0);
            cr1 = __builtin_amdgcn_mfma_f32_16x16x32_f16(ahi11, bl1, cr1, 0, 0, 0);
            cr1 = __builtin_amdgcn_mfma_f32_16x16x32_f16(alo10, bh0, cr1, 0, 0, 0);
            cr1 = __builtin_amdgcn_mfma_f32_16x16x32_f16(alo11, bh1, cr1, 0, 0, 0);
            UPDP(b1_10, b2_10, __fmaf_rn(-INV2LO, cr1[0], __fmaf_rn(-2.0f, hh1[0], cs)))
            UPDP(b1_11, b2_11, __fmaf_rn(-INV2LO, cr1[1], __fmaf_rn(-2.0f, hh1[1], cs)))
            UPDP(b1_12, b2_12, __fmaf_rn(-INV2LO, cr1[2], __fmaf_rn(-2.0f, hh1[2], cs)))
            UPDP(b1_13, b2_13, __fmaf_rn(-INV2LO, cr1[3], __fmaf_rn(-2.0f, hh1[3], cs)))

            base0 += 2048;
            csi += 16;
        }
    }

    // Best-2 merge across the 16 lanes of each row-group. Cross-lane stripped
    // ties -> gap 0 -> flagged -> exact rescore.
#pragma unroll
    for (int dd = 1; dd < 16; dd <<= 1) {
        MRGP(b1_00, b2_00) MRGP(b1_01, b2_01) MRGP(b1_02, b2_02) MRGP(b1_03, b2_03)
        MRGP(b1_10, b2_10) MRGP(b1_11, b2_11) MRGP(b1_12, b2_12) MRGP(b1_13, b2_13)
    }

    if (lrow == 0) {
        FLAGP(0, 0, b1_00, b2_00) FLAGP(0, 1, b1_01, b2_01)
        FLAGP(0, 2, b1_02, b2_02) FLAGP(0, 3, b1_03, b2_03)
        FLAGP(1, 0, b1_10, b2_10) FLAGP(1, 1, b1_11, b2_11)
        FLAGP(1, 2, b1_12, b2_12) FLAGP(1, 3, b1_13, b2_13)
    }
    __syncthreads();

    // In-kernel exact rescore: one wave per flagged point, lanes own 8
    // centroids. Bit-identical np-replica distance (proven absmax=0 R1-R7).
    // First-index-wins via packed (distbits<<32)|k min (dist > 0 always).
    int n = *lcnt;
    if (n > SLICE) n = SLICE;
    for (int t = wid; t < n; t += 8) {
        int i = __builtin_amdgcn_readfirstlane(llist[t]);
        const float* xr = x + (size_t)i * DD;   // wave-uniform -> s_loads

        float r8[8];
#pragma unroll
        for (int e = 0; e < 8; ++e) r8[e] = __fmul_rn(xr[e], xr[e]);
#pragma unroll
        for (int blk = 1; blk < 8; ++blk)
#pragma unroll
            for (int e = 0; e < 8; ++e)
                r8[e] = __fadd_rn(r8[e], __fmul_rn(xr[8 * blk + e], xr[8 * blk + e]));
        float x_sq = __fadd_rn(__fadd_rn(__fadd_rn(r8[0], r8[1]), __fadd_rn(r8[2], r8[3])),
                               __fadd_rn(__fadd_rn(r8[4], r8[5]), __fadd_rn(r8[6], r8[7])));

        unsigned long long best = ~0ull;
#pragma unroll
        for (int j = 0; j < 8; ++j) {
            int k = j * 64 + lane;
            const float* crow = c + (size_t)k * DD;
            float a0 = 0.f, a1 = 0.f, a2 = 0.f, a3 = 0.f;
#pragma unroll
            for (int d = 0; d < DD; d += 4) {
                a0 = __fmaf_rn(xr[d + 0], crow[d + 0], a0);
                a1 = __fmaf_rn(xr[d + 1], crow[d + 1], a1);
                a2 = __fmaf_rn(xr[d + 2], crow[d + 2], a2);
                a3 = __fmaf_rn(xr[d + 3], crow[d + 3], a3);
            }
            float acc = __fadd_rn(__fadd_rn(a0, a1), __fadd_rn(a2, a3));
            float tt = __fadd_rn(x_sq, csq[k]);
            float dist = __fmaf_rn(-2.0f, acc, tt);
            unsigned long long key =
                ((unsigned long long)__float_as_uint(dist) << 32) | (unsigned)k;
            best = best < key ? best : key;
        }
#pragma unroll
        for (int dd = 1; dd < 64; dd <<= 1) {
            unsigned hi = (unsigned)__shfl_xor((int)(best >> 32), dd);
            unsigned lo = (unsigned)__shfl_xor((int)(best & 0xFFFFFFFFull), dd);
            unsigned long long o = ((unsigned long long)hi << 32) | lo;
            best = best < o ? best : o;
        }
        if (lane == 0) out_assign[i] = (float)(unsigned)(best & 0xFFFFFFFFull);
    }
}

extern "C" void kernel_launch(void* const* d_in, const int* in_sizes, int n_in,
                              void* d_out, int out_size, void* d_ws, size_t ws_size,
                              hipStream_t stream) {
    const float* x = (const float*)d_in[0];
    const float* c = (const float*)d_in[1];
    float* out = (float*)d_out;
    float* out_assign = out + KC * DD;
    float* csq = (float*)d_ws;   // 2 KB of d_ws, nothing else

    prep_kernel<<<(KC * DD + 255) / 256, 256, 0, stream>>>(c, out, csq);
    approx_kernel<<<NPTS / PPB, BLOCK, 68624, stream>>>(x, c, csq, out_assign);
}

// Round 9
// 159.585 us; speedup vs baseline: 3.1281x; 3.1281x over previous
//
#include <hip/hip_runtime.h>
#include <math.h>

#define NPTS 262144
#define KC 512
#define DD 64
#define MARGIN 1e-3f
#define LOSCALE 2048.0f
#define INV2LO 0.0009765625f   // 2 / LOSCALE = 2^-10
#define SLICE 128              // == points/block -> llist cannot overflow

typedef _Float16 f16x8 __attribute__((ext_vector_type(8)));
typedef _Float16 f16x4 __attribute__((ext_vector_type(4)));
typedef float f32x4 __attribute__((ext_vector_type(4)));

__device__ __forceinline__ float csq_pairwise8(const float* row) {
    float r[8];
#pragma unroll
    for (int t = 0; t < 8; ++t) r[t] = __fmul_rn(row[t], row[t]);
#pragma unroll
    for (int b = 1; b < 8; ++b)
#pragma unroll
        for (int t = 0; t < 8; ++t)
            r[t] = __fadd_rn(r[t], __fmul_rn(row[8 * b + t], row[8 * b + t]));
    return __fadd_rn(__fadd_rn(__fadd_rn(r[0], r[1]), __fadd_rn(r[2], r[3])),
                     __fadd_rn(__fadd_rn(r[4], r[5]), __fadd_rn(r[6], r[7])));
}

__global__ __launch_bounds__(256) void prep_kernel(const float* __restrict__ c,
                                                   float* __restrict__ out_c,
                                                   float* __restrict__ csq) {
    int j = blockIdx.x * 256 + threadIdx.x;
    if (j < KC * DD) out_c[j] = c[j];
    if (j < KC) csq[j] = csq_pairwise8(c + j * DD);
}

// EXACT R5 kernel shape (the only split-f16 build that compiled clean: 118us
// total, no spill). Sole changes vs R5: flag list lives in LDS (SLICE==points/
// block, can't overflow) and the exact rescore runs in-kernel -> d_ws holds
// only csq (2 KB). R6/R7/R8 deviations (BLOCK=512, named scalars, (512,4)
// bounds, packed keys) each re-triggered allocator spill (94-819 MB WRITE).
__global__ __launch_bounds__(256, 2) void approx_kernel(const float* __restrict__ x,
                                                        const float* __restrict__ c,
                                                        const float* __restrict__ csq,
                                                        float* __restrict__ out_assign) {
    extern __shared__ char smem[];          // [0,32K) c_hi | [32K,64K) c_lo'
    float* scs = (float*)(smem + 65536);    // 512 f32
    int* llist = (int*)(smem + 67584);      // 128 int flagged point ids
    int* lcnt = (int*)(smem + 68096);

    int tid = threadIdx.x;
    if (tid == 0) *lcnt = 0;
    scs[tid] = csq[tid];
    scs[tid + 256] = csq[tid + 256];

    int wid = tid >> 6, lane = tid & 63;
    int lrow = lane & 15, lgrp = lane >> 4;
    int pbase = blockIdx.x * 128 + wid * 32;

    // A fragments (layout verified absmax=0 in R4-R8): row=lane&15,
    // k-elems kk*32+lgrp*8. Split x = hi + lo'/2048 (lo' f16-normal).
    f16x8 ahi[2][2], alo[2][2];
#pragma unroll
    for (int s = 0; s < 2; ++s)
#pragma unroll
        for (int kk = 0; kk < 2; ++kk) {
            const float4* p = (const float4*)(x + (size_t)(pbase + s * 16 + lrow) * DD
                                              + kk * 32 + lgrp * 8);
            float4 u0 = p[0], u1 = p[1];
            float f[8] = {u0.x, u0.y, u0.z, u0.w, u1.x, u1.y, u1.z, u1.w};
            f16x8 h, l;
#pragma unroll
            for (int e = 0; e < 8; ++e) {
                _Float16 hh = (_Float16)f[e];
                h[e] = hh;
                l[e] = (_Float16)((f[e] - (float)hh) * LOSCALE);
            }
            ahi[s][kk] = h;
            alo[s][kk] = l;
        }

    float b1[2][4], b2[2][4];
    int k1[2][4];
#pragma unroll
    for (int s = 0; s < 2; ++s)
#pragma unroll
        for (int r = 0; r < 4; ++r) { b1[s][r] = INFINITY; b2[s][r] = INFINITY; k1[s][r] = 0; }

    for (int pass = 0; pass < 2; ++pass) {
        __syncthreads();   // covers scs/lcnt staging on pass 0; pass-0 reads on pass 1
        // Stage 256 centroid rows: fp32 -> (hi, lo') f16, XOR-swizzled.
        const float4* csrc = (const float4*)(c + (size_t)pass * 256 * DD);
#pragma unroll
        for (int it = 0; it < 16; ++it) {
            int chunk = tid + it * 256;                 // 4096 x 16B-src chunks
            int row = chunk >> 4, q = chunk & 15;
            float4 v = csrc[chunk];
            f16x4 h, l;
            _Float16 t;
            t = (_Float16)v.x; h[0] = t; l[0] = (_Float16)((v.x - (float)t) * LOSCALE);
            t = (_Float16)v.y; h[1] = t; l[1] = (_Float16)((v.y - (float)t) * LOSCALE);
            t = (_Float16)v.z; h[2] = t; l[2] = (_Float16)((v.z - (float)t) * LOSCALE);
            t = (_Float16)v.w; h[3] = t; l[3] = (_Float16)((v.w - (float)t) * LOSCALE);
            int off = row * 128 + (((q >> 1) ^ (row & 7)) << 4) + (q & 1) * 8;
            *(f16x4*)(smem + off) = h;
            *(f16x4*)(smem + 32768 + off) = l;
        }
        __syncthreads();

        int base0 = lrow * 128 + ((lgrp ^ (lrow & 7)) << 4);
        int csi = pass * 256 + lrow;
#pragma unroll 2
        for (int ct = 0; ct < 16; ++ct) {
            f16x8 bh0 = *(const f16x8*)(smem + base0);
            f16x8 bh1 = *(const f16x8*)(smem + (base0 ^ 64));
            f16x8 bl0 = *(const f16x8*)(smem + 32768 + base0);
            f16x8 bl1 = *(const f16x8*)(smem + 32768 + (base0 ^ 64));
            float cs = scs[csi];
            int kv = csi;
#pragma unroll
            for (int s = 0; s < 2; ++s) {
                f32x4 hh = {0.f, 0.f, 0.f, 0.f}, cr = {0.f, 0.f, 0.f, 0.f};
                hh = __builtin_amdgcn_mfma_f32_16x16x32_f16(ahi[s][0], bh0, hh, 0, 0, 0);
                hh = __builtin_amdgcn_mfma_f32_16x16x32_f16(ahi[s][1], bh1, hh, 0, 0, 0);
                cr = __builtin_amdgcn_mfma_f32_16x16x32_f16(ahi[s][0], bl0, cr, 0, 0, 0);
                cr = __builtin_amdgcn_mfma_f32_16x16x32_f16(ahi[s][1], bl1, cr, 0, 0, 0);
                cr = __builtin_amdgcn_mfma_f32_16x16x32_f16(alo[s][0], bh0, cr, 0, 0, 0);
                cr = __builtin_amdgcn_mfma_f32_16x16x32_f16(alo[s][1], bh1, cr, 0, 0, 0);
#pragma unroll
                for (int r = 0; r < 4; ++r) {
                    float d = __fmaf_rn(-INV2LO, cr[r], __fmaf_rn(-2.0f, hh[r], cs));
                    bool lt = d < b1[s][r];
                    b2[s][r] = fminf(b2[s][r], fmaxf(b1[s][r], d));
                    b1[s][r] = fminf(b1[s][r], d);
                    k1[s][r] = lt ? kv : k1[s][r];
                }
            }
            base0 += 2048;
            csi += 16;
        }
    }

    // Merge best-2 across the 16 lanes of each row-group. Cross-lane ties leave
    // gap==0 -> flagged -> exact rescore, so tie k-direction is free.
#pragma unroll
    for (int dd = 1; dd < 16; dd <<= 1)
#pragma unroll
        for (int s = 0; s < 2; ++s)
#pragma unroll
            for (int r = 0; r < 4; ++r) {
                float o1 = __shfl_xor(b1[s][r], dd);
                float o2 = __shfl_xor(b2[s][r], dd);
                int ok = __shfl_xor(k1[s][r], dd);
                b2[s][r] = fminf(fminf(b2[s][r], o2), fmaxf(b1[s][r], o1));
                bool lt = o1 < b1[s][r];
                b1[s][r] = fminf(b1[s][r], o1);
                k1[s][r] = lt ? ok : k1[s][r];
            }

    // Flag phase: ambiguous points go to the LDS list (bounded by 128 ==
    // points/block; fallback write keeps single-writer even if logic drifts).
    if (lrow == 0) {
#pragma unroll
        for (int s = 0; s < 2; ++s)
#pragma unroll
            for (int r = 0; r < 4; ++r) {
                int p = pbase + s * 16 + lgrp * 4 + r;   // C/D row=(lane>>4)*4+reg
                if (b2[s][r] - b1[s][r] <= MARGIN) {
                    int t = atomicAdd(lcnt, 1);          // LDS atomic only
                    if (t < SLICE) llist[t] = p;
                    else out_assign[p] = (float)k1[s][r];
                } else {
                    out_assign[p] = (float)k1[s][r];
                }
            }
    }
    __syncthreads();

    // In-kernel exact rescore: one wave per flagged point, lanes own 8
    // centroids. Bit-identical np-replica distance (proven absmax=0 R1-R8).
    // First-index-wins via packed (distbits<<32)|k min (dist > 0 always).
    int n = *lcnt;
    if (n > SLICE) n = SLICE;
    for (int t = wid; t < n; t += 4) {
        int i = __builtin_amdgcn_readfirstlane(llist[t]);
        const float* xr = x + (size_t)i * DD;   // wave-uniform -> s_loads

        float r8[8];
#pragma unroll
        for (int e = 0; e < 8; ++e) r8[e] = __fmul_rn(xr[e], xr[e]);
#pragma unroll
        for (int blk = 1; blk < 8; ++blk)
#pragma unroll
            for (int e = 0; e < 8; ++e)
                r8[e] = __fadd_rn(r8[e], __fmul_rn(xr[8 * blk + e], xr[8 * blk + e]));
        float x_sq = __fadd_rn(__fadd_rn(__fadd_rn(r8[0], r8[1]), __fadd_rn(r8[2], r8[3])),
                               __fadd_rn(__fadd_rn(r8[4], r8[5]), __fadd_rn(r8[6], r8[7])));

        unsigned long long best = ~0ull;
#pragma unroll
        for (int j = 0; j < 8; ++j) {
            int k = j * 64 + lane;
            const float* crow = c + (size_t)k * DD;
            float a0 = 0.f, a1 = 0.f, a2 = 0.f, a3 = 0.f;
#pragma unroll
            for (int d = 0; d < DD; d += 4) {
                a0 = __fmaf_rn(xr[d + 0], crow[d + 0], a0);
                a1 = __fmaf_rn(xr[d + 1], crow[d + 1], a1);
                a2 = __fmaf_rn(xr[d + 2], crow[d + 2], a2);
                a3 = __fmaf_rn(xr[d + 3], crow[d + 3], a3);
            }
            float acc = __fadd_rn(__fadd_rn(a0, a1), __fadd_rn(a2, a3));
            float tt = __fadd_rn(x_sq, csq[k]);
            float dist = __fmaf_rn(-2.0f, acc, tt);
            unsigned long long key =
                ((unsigned long long)__float_as_uint(dist) << 32) | (unsigned)k;
            best = best < key ? best : key;
        }
#pragma unroll
        for (int dd = 1; dd < 64; dd <<= 1) {
            unsigned hi = (unsigned)__shfl_xor((int)(best >> 32), dd);
            unsigned lo = (unsigned)__shfl_xor((int)(best & 0xFFFFFFFFull), dd);
            unsigned long long o = ((unsigned long long)hi << 32) | lo;
            best = best < o ? best : o;
        }
        if (lane == 0) out_assign[i] = (float)(unsigned)(best & 0xFFFFFFFFull);
    }
}

extern "C" void kernel_launch(void* const* d_in, const int* in_sizes, int n_in,
                              void* d_out, int out_size, void* d_ws, size_t ws_size,
                              hipStream_t stream) {
    const float* x = (const float*)d_in[0];
    const float* c = (const float*)d_in[1];
    float* out = (float*)d_out;
    float* out_assign = out + KC * DD;
    float* csq = (float*)d_ws;   // 2 KB of d_ws, nothing else

    prep_kernel<<<(KC * DD + 255) / 256, 256, 0, stream>>>(c, out, csq);
    approx_kernel<<<NPTS / 128, 256, 68112, stream>>>(x, c, csq, out_assign);
}